// Round 1
// baseline (397.571 us; speedup 1.0000x reference)
//
#include <hip/hip_runtime.h>

#define T_STEPS 256
#define BATCH   512
#define DIN     256
#define HDIM    256

__device__ __forceinline__ float fast_sigmoid(float x) {
    return 1.0f / (1.0f + __expf(-x));
}
__device__ __forceinline__ float fast_tanh(float x) {
    return 1.0f - 2.0f / (__expf(2.0f * x) + 1.0f);
}

// c = {c0..c7} in two float4s; returns sum_q out_q * W[q] where
// out_0 = c1*...*c7, out_i = c0*...*ci (i>=1). W indexed statically.
__device__ __forceinline__ float group_dot(const float4 cA, const float4 cB, const float* W) {
    float pr = cA.x;          // c0
    float d  = 0.0f;
    pr *= cA.y; d = fmaf(pr, W[1], d);
    pr *= cA.z; d = fmaf(pr, W[2], d);
    pr *= cA.w; d = fmaf(pr, W[3], d);
    pr *= cB.x; d = fmaf(pr, W[4], d);
    pr *= cB.y; d = fmaf(pr, W[5], d);
    pr *= cB.z; d = fmaf(pr, W[6], d);
    pr *= cB.w; d = fmaf(pr, W[7], d);
    float sf = (cA.y * cA.z) * (cA.w * cB.x);
    sf *= (cB.y * cB.z) * cB.w;
    d = fmaf(sf, W[0], d);
    return d;
}

__launch_bounds__(256, 2)
__global__ void qlstm_kernel(const float* __restrict__ inputs,
                             const float* __restrict__ W_proj,
                             const float* __restrict__ b_proj,
                             const float* __restrict__ theta_gate,
                             const float* __restrict__ W_qproj,
                             const float* __restrict__ b_qproj,
                             const float* __restrict__ theta_attn,
                             const float* __restrict__ W_attn_proj,
                             const float* __restrict__ b_attn_proj,
                             const float* __restrict__ W_attn_back,
                             const float* __restrict__ b_attn_back,
                             float* __restrict__ out) {
    const int tid = threadIdx.x;
    const int b   = blockIdx.x;
    const int g   = tid >> 3;   // gate index 0..31
    const int j   = tid & 7;    // k-chunk within gate's 512-dot
    const int o   = tid >> 5;   // attn output 0..7
    const int p   = tid & 31;   // partial index for attn reduce

    // xh: [x(256) | h(256)], 4-float pad per 64 -> conflict-free chunked float4 reads
    __shared__ __align__(16) float xh[544];
    __shared__ float hm[288];                 // hx_mid, +1 pad per 8
    __shared__ __align__(16) float cg[32];    // gate cosines
    __shared__ __align__(16) float ca[8];     // attn cosines

    // ---- one-time weight preload into registers ----
    float Wr[64];
    #pragma unroll
    for (int i = 0; i < 64; ++i)
        Wr[i] = W_proj[(j * 64 + i) * 32 + g];

    float Wqp[8], Wab[8], Wap[8];
    #pragma unroll
    for (int q = 0; q < 8; ++q) {
        Wqp[q] = W_qproj[q * 256 + tid];
        Wab[q] = W_attn_back[q * 256 + tid];
        Wap[q] = W_attn_proj[(p * 8 + q) * 8 + o];
    }
    const float bp  = b_proj[g];
    const float thg = theta_gate[g & 7];
    const float bqp = b_qproj[tid];
    const float bap = b_attn_proj[o];
    const float tha = theta_attn[o];
    const float bab = b_attn_back[tid];

    // ---- init state: x_0 staged, h = 0, c = 0 ----
    xh[tid + ((tid >> 6) << 2)] = inputs[(size_t)b * DIN + tid];
    {
        const int k = 256 + tid;
        xh[k + ((k >> 6) << 2)] = 0.0f;
    }
    float cx = 0.0f;
    float hx_new = 0.0f;
    __syncthreads();

    for (int t = 0; t < T_STEPS; ++t) {
        // prefetch next timestep's x (consumed at loop bottom)
        float xn = 0.0f;
        if (t + 1 < T_STEPS)
            xn = inputs[((size_t)(t + 1) * BATCH + b) * DIN + tid];

        // ---- Phase A: gates = [x|h] @ W_proj, 8 lanes per gate ----
        float acc = 0.0f;
        {
            const float4* xv = reinterpret_cast<const float4*>(&xh[j * 68]);
            #pragma unroll
            for (int i4 = 0; i4 < 16; ++i4) {
                float4 v = xv[i4];
                acc = fmaf(Wr[4 * i4 + 0], v.x, acc);
                acc = fmaf(Wr[4 * i4 + 1], v.y, acc);
                acc = fmaf(Wr[4 * i4 + 2], v.z, acc);
                acc = fmaf(Wr[4 * i4 + 3], v.w, acc);
            }
        }
        acc += __shfl_xor(acc, 1);
        acc += __shfl_xor(acc, 2);
        acc += __shfl_xor(acc, 4);
        if (j == 0)
            cg[g] = __cosf(acc + bp + thg);   // c_q for gate g (q = g&7)
        __syncthreads();

        // ---- Phase B/C: qp + activations + LSTM cell (thread = h) ----
        float dots[4];
        #pragma unroll
        for (int G = 0; G < 4; ++G) {
            float4 cA = *reinterpret_cast<const float4*>(&cg[G * 8]);
            float4 cB = *reinterpret_cast<const float4*>(&cg[G * 8 + 4]);
            dots[G] = group_dot(cA, cB, Wqp) + bqp;
        }
        float fv = fast_sigmoid(dots[0]);
        float iv = fast_sigmoid(dots[1]);
        float gv = fast_tanh(dots[2]);
        float ov = fast_sigmoid(dots[3]);
        cx = fmaf(fv, cx, iv * gv);
        float hmid = ov * fast_tanh(cx);
        hm[tid + (tid >> 3)] = hmid;
        __syncthreads();

        // ---- Phase D: attn_in = hmid @ W_attn_proj (32 lanes per output) ----
        float s = 0.0f;
        #pragma unroll
        for (int m = 0; m < 8; ++m)
            s = fmaf(Wap[m], hm[p * 9 + m], s);
        s += __shfl_xor(s, 1);
        s += __shfl_xor(s, 2);
        s += __shfl_xor(s, 4);
        s += __shfl_xor(s, 8);
        s += __shfl_xor(s, 16);
        if (p == 0)
            ca[o] = __cosf(s + bap + tha);
        __syncthreads();

        // ---- Phase E: hx_new = qgate(attn) @ W_attn_back + b ----
        {
            float4 cA = *reinterpret_cast<const float4*>(&ca[0]);
            float4 cB = *reinterpret_cast<const float4*>(&ca[4]);
            hx_new = group_dot(cA, cB, Wab) + bab;
        }
        out[((size_t)t * BATCH + b) * HDIM + tid] = hx_new;
        {
            const int k = 256 + tid;
            xh[k + ((k >> 6) << 2)] = hx_new;
        }
        if (t + 1 < T_STEPS)
            xh[tid + ((tid >> 6) << 2)] = xn;
        __syncthreads();
    }

    // ---- final (hx, cx) ----
    const size_t base = (size_t)T_STEPS * BATCH * HDIM;
    out[base + (size_t)b * HDIM + tid] = hx_new;
    out[base + (size_t)BATCH * HDIM + (size_t)b * HDIM + tid] = cx;
}

extern "C" void kernel_launch(void* const* d_in, const int* in_sizes, int n_in,
                              void* d_out, int out_size, void* d_ws, size_t ws_size,
                              hipStream_t stream) {
    const float* inputs      = (const float*)d_in[0];
    const float* W_proj      = (const float*)d_in[1];
    const float* b_proj      = (const float*)d_in[2];
    const float* theta_gate  = (const float*)d_in[3];
    const float* W_qproj     = (const float*)d_in[4];
    const float* b_qproj     = (const float*)d_in[5];
    const float* theta_attn  = (const float*)d_in[6];
    const float* W_attn_proj = (const float*)d_in[7];
    const float* b_attn_proj = (const float*)d_in[8];
    const float* W_attn_back = (const float*)d_in[9];
    const float* b_attn_back = (const float*)d_in[10];
    float* outp = (float*)d_out;

    qlstm_kernel<<<BATCH, 256, 0, stream>>>(inputs, W_proj, b_proj, theta_gate,
                                            W_qproj, b_qproj, theta_attn,
                                            W_attn_proj, b_attn_proj,
                                            W_attn_back, b_attn_back, outp);
}